// Round 5
// baseline (133.771 us; speedup 1.0000x reference)
//
#include <hip/hip_runtime.h>
#include <math.h>

// B=16384, S=64, V=25, E=64, H=64, 4H=256, C=3
// gates[B,256] = x[B,89] @ W^T via mfma_f32_16x16x32_bf16, K = 3 chunks of 32:
// chunk0 = msg k=0..24, k=25 carries 1.0 (bias row), pad 0; chunk1/2 = h bf16.
// Block = 2 waves (128 thr) = 16 batch rows; wave p owns units [32p,32p+32) x 4 gates
// (8 tiles, acc[4][2], 8 cells/thread) -> activations wave-local, 2-wave barrier.

using bf16x8 = __attribute__((ext_vector_type(8))) short;
using f32x4  = __attribute__((ext_vector_type(4))) float;

__device__ __forceinline__ unsigned short f2bf(float x) {
    unsigned int u = __float_as_uint(x);
    u += 0x7FFFu + ((u >> 16) & 1u);           // RNE
    return (unsigned short)(u >> 16);
}
__device__ __forceinline__ float bf2f(unsigned short h) {
    return __uint_as_float(((unsigned int)h) << 16);
}

// B-fragment layout for 16x16x32: lane holds B[k=(lane>>4)*8+j][col=(lane&15)+16*tile].
// wfrag[((ch*16+t)*64+lane)*8+j], bf16. ch0: comb[k][g] (k<25), k==25 -> bias; ch1/2: Whh[g][k].
__global__ void prep_kernel(const float* __restrict__ emb,
                            const float* __restrict__ Wih,
                            const float* __restrict__ Whh,
                            const float* __restrict__ bih,
                            const float* __restrict__ bhh,
                            unsigned short* __restrict__ wfrag) {
    const int b = blockIdx.x, tid = threadIdx.x;
    const int ch = b >> 4, t = b & 15;
    const int lane = tid >> 3, j = tid & 7;
    const int kloc = (lane >> 4) * 8 + j;       // 0..31
    const int g = (lane & 15) + 16 * t;         // 0..255
    float v = 0.f;
    if (ch == 0) {
        if (kloc < 25) {
            const float* ep = emb + kloc * 64;
            const float* wp = Wih + g * 64;
            float s = 0.f;
            #pragma unroll
            for (int e = 0; e < 64; ++e) s = fmaf(ep[e], wp[e], s);
            v = s;
        } else if (kloc == 25) {
            v = bih[g] + bhh[g];                // bias row (exact: 0.0 / 1.0)
        }
    } else {
        v = Whh[g * 64 + (ch - 1) * 32 + kloc];
    }
    wfrag[((ch * 16 + t) * 64 + lane) * 8 + j] = f2bf(v);
}

#define LOADMSG(DST, SS)                                                     \
    {                                                                        \
        const float* p_ = mrow + (SS) * 25 + kq;                             \
        if (kq < 24) {                                                       \
            _Pragma("unroll") for (int j = 0; j < 8; ++j)                    \
                DST[j] = (short)f2bf(p_[j]);                                 \
        } else {                                                             \
            DST[0] = (short)f2bf(p_[0]);                                     \
            DST[1] = (short)0x3F80;   /* 1.0 -> bias row k=25 */             \
            _Pragma("unroll") for (int j = 2; j < 8; ++j) DST[j] = 0;        \
        }                                                                    \
    }

#define KE 1.4426950408889634f
#define K2E 2.8853900817779268f

#define STEP(S, CURB, NXTB, MC, MN)                                          \
    {                                                                        \
        if ((S) < 63) LOADMSG(MN, (S) + 1)                                   \
        bf16x8 ah[2];                                                        \
        _Pragma("unroll") for (int ch = 0; ch < 2; ++ch) {                   \
            int off_ = (l16 * 128 + ch * 64 + kq * 2) ^ swz_rd;              \
            ah[ch] = *(const bf16x8*)((CURB) + off_);                        \
        }                                                                    \
        f32x4 acc[4][2];                                                     \
        _Pragma("unroll") for (int i = 0; i < 4; ++i)                        \
            _Pragma("unroll") for (int u = 0; u < 2; ++u)                    \
                acc[i][u] = (f32x4){0.f, 0.f, 0.f, 0.f};                     \
        _Pragma("unroll") for (int i = 0; i < 4; ++i)                        \
            _Pragma("unroll") for (int u = 0; u < 2; ++u)                    \
                acc[i][u] = __builtin_amdgcn_mfma_f32_16x16x32_bf16(         \
                    MC, w[0][i][u], acc[i][u], 0, 0, 0);                     \
        _Pragma("unroll") for (int ch = 0; ch < 2; ++ch)                     \
            _Pragma("unroll") for (int i = 0; i < 4; ++i)                    \
                _Pragma("unroll") for (int u = 0; u < 2; ++u)                \
                    acc[i][u] = __builtin_amdgcn_mfma_f32_16x16x32_bf16(     \
                        ah[ch], w[1 + ch][i][u], acc[i][u], 0, 0, 0);        \
        _Pragma("unroll") for (int u = 0; u < 2; ++u)                        \
            _Pragma("unroll") for (int q = 0; q < 4; ++q) {                  \
                float ai = acc[0][u][q], af = acc[1][u][q];                  \
                float ag = acc[2][u][q], ao = acc[3][u][q];                  \
                float ti = __builtin_amdgcn_exp2f(-KE * ai);                 \
                float tf = __builtin_amdgcn_exp2f(-KE * af);                 \
                float to = __builtin_amdgcn_exp2f(-KE * ao);                 \
                float tg = __builtin_amdgcn_exp2f(-K2E * fabsf(ag));         \
                float ig = (1.f - tg) *                                      \
                    __builtin_amdgcn_rcpf((1.f + ti) * (1.f + tg));          \
                ig = copysignf(ig, ag);                                      \
                float fg = __builtin_amdgcn_rcpf(1.f + tf);                  \
                float cn = fmaf(fg, c[u][q], ig);                            \
                c[u][q] = cn;                                                \
                float tc = __builtin_amdgcn_exp2f(-K2E * fabsf(cn));         \
                float hn = (1.f - tc) *                                      \
                    __builtin_amdgcn_rcpf((1.f + to) * (1.f + tc));          \
                hn = copysignf(hn, cn);                                      \
                int rw_ = lq * 4 + q;                                        \
                int offw_ = (rw_ * 128 + (32 * p + 16 * u + l16) * 2)        \
                            ^ ((rw_ & 7) << 4);                              \
                *(unsigned short*)((NXTB) + offw_) = f2bf(hn);               \
            }                                                                \
        __syncthreads();                                                     \
    }

__global__ __launch_bounds__(128, 2) void lstm_mfma(
    const float* __restrict__ msgs,
    const unsigned short* __restrict__ wfrag,
    const float* __restrict__ fcw,
    const float* __restrict__ fcb,
    float* __restrict__ out)
{
    // double-buffered h: buf = h[16 rows][64 units] bf16 = 2KB, x2
    __shared__ __align__(16) char lds[4096];

    const int tid  = threadIdx.x;
    const int lane = tid & 63;
    const int p    = __builtin_amdgcn_readfirstlane(tid >> 6); // 0..1 (SGPR)
    const int l16  = lane & 15;
    const int lq   = lane >> 4;
    const int row0 = blockIdx.x * 16;
    const int kq   = lq * 8;                   // k base within chunk

    // weight fragments in VGPRs: tiles 4i + 2p + u (gate i, unit-group), 3 chunks
    bf16x8 w[3][4][2];
    #pragma unroll
    for (int ch = 0; ch < 3; ++ch)
        #pragma unroll
        for (int i = 0; i < 4; ++i)
            #pragma unroll
            for (int u = 0; u < 2; ++u)
                w[ch][i][u] = *(const bf16x8*)(
                    wfrag + ((ch * 16 + 4 * i + 2 * p + u) * 64 + lane) * 8);

    // zero h buffer 0 (2KB)
    for (int idx = tid; idx < 512; idx += 128) ((unsigned int*)lds)[idx] = 0u;

    float c[2][4] = {{0.f, 0.f, 0.f, 0.f}, {0.f, 0.f, 0.f, 0.f}};

    const float* mrow = msgs + (long)(row0 + l16) * 1600;
    const int swz_rd  = (l16 & 7) << 4;

    bf16x8 m0, m1;
    LOADMSG(m0, 0)
    __syncthreads();

    char* b0 = (char*)lds;
    char* b1 = b0 + 2048;
    for (int s2 = 0; s2 < 64; s2 += 2) {
        STEP(s2,     b0, b1, m0, m1)
        STEP(s2 + 1, b1, b0, m1, m0)
    }

    // final h in b0. FC epilogue: thread -> (row, class)
    if (tid < 64) {
        const int r = tid >> 2, cls = tid & 3;
        if (cls < 3) {
            float a = fcb[cls];
            const int swz = (r & 7) << 4;
            #pragma unroll
            for (int u = 0; u < 64; ++u) {
                int off = (r * 128 + u * 2) ^ swz;
                float hv = bf2f(*(const unsigned short*)(b0 + off));
                a = fmaf(hv, fcw[cls * 64 + u], a);
            }
            out[(row0 + r) * 3 + cls] = a;
        }
    }
}

extern "C" void kernel_launch(void* const* d_in, const int* in_sizes, int n_in,
                              void* d_out, int out_size, void* d_ws, size_t ws_size,
                              hipStream_t stream) {
    const float* msgs = (const float*)d_in[0];
    const float* emb  = (const float*)d_in[1];
    const float* Wih  = (const float*)d_in[2];
    const float* Whh  = (const float*)d_in[3];
    const float* bih  = (const float*)d_in[4];
    const float* bhh  = (const float*)d_in[5];
    const float* fcw  = (const float*)d_in[6];
    const float* fcb  = (const float*)d_in[7];
    float* out = (float*)d_out;

    // ws: wfrag bf16[3*16*64*8] = 49152 B
    unsigned short* wfrag = (unsigned short*)d_ws;

    prep_kernel<<<48, 512, 0, stream>>>(emb, Wih, Whh, bih, bhh, wfrag);
    lstm_mfma<<<16384 / 16, 128, 0, stream>>>(msgs, wfrag, fcw, fcb, out);
}

// Round 6
// 112.279 us; speedup vs baseline: 1.1914x; 1.1914x over previous
//
#include <hip/hip_runtime.h>
#include <math.h>

// B=16384, S=64, V=25, E=64, H=64, 4H=256, C=3
// gates^T[gunit][brow] = W_fused[gunit][k] @ x^T[k][brow] via mfma_f32_16x16x32_bf16.
// A = weights (VGPR-stationary), B = activations (msg from global, h from LDS).
// K = 3 chunks of 32: ch0 = msg k=0..24 (+k=25 bias row, 1.0 in B), ch1/2 = h bf16.
// Weights pre-scaled: i,f,o rows by -log2(e); g rows by +2*log2(e) -> no runtime muls.
// Block = 4 waves (256 thr) = 16 batch rows; wave cg owns h-units [16cg,16cg+16).

using bf16x8 = __attribute__((ext_vector_type(8))) short;
using f32x4  = __attribute__((ext_vector_type(4))) float;

union U16B { uint4 u; bf16x8 v; };

#define KE  1.4426950408889634f
#define K2E 2.8853900817779268f

__device__ __forceinline__ unsigned short f2bf(float x) {
    unsigned int u = __float_as_uint(x);
    u += 0x7FFFu + ((u >> 16) & 1u);           // RNE
    return (unsigned short)(u >> 16);
}
__device__ __forceinline__ float bf2f(unsigned short h) {
    return __uint_as_float(((unsigned int)h) << 16);
}

// A-fragment layout for 16x16x32: lane holds A[row=lane&15][k=(lane>>4)*8+j], j=0..7.
// wfrag[((ch*16+gt)*64+lane)*8+j]: tile gt covers gunits [16gt,16gt+16).
// ch0: combT[gunit][k] = sum_e emb[k][e]*Wih[gunit][e] (k<25), k==25 -> bias; ch1/2: Whh[gunit][k].
// All values pre-scaled by s(gate): gate=gunit>>6 (i,f,g,o); s = (gate==2)? +K2E : -KE.
__global__ void prep_kernel(const float* __restrict__ emb,
                            const float* __restrict__ Wih,
                            const float* __restrict__ Whh,
                            const float* __restrict__ bih,
                            const float* __restrict__ bhh,
                            unsigned short* __restrict__ wfrag) {
    const int b = blockIdx.x, tid = threadIdx.x;
    const int ch = b >> 4, gt = b & 15;
    const int lane = tid >> 3, j = tid & 7;
    const int kloc = (lane >> 4) * 8 + j;       // 0..31
    const int gunit = 16 * gt + (lane & 15);    // 0..255
    float v = 0.f;
    if (ch == 0) {
        if (kloc < 25) {
            const float* ep = emb + kloc * 64;
            const float* wp = Wih + gunit * 64;
            float s = 0.f;
            #pragma unroll
            for (int e = 0; e < 64; ++e) s = fmaf(ep[e], wp[e], s);
            v = s;
        } else if (kloc == 25) {
            v = bih[gunit] + bhh[gunit];        // bias row
        }
    } else {
        v = Whh[gunit * 64 + (ch - 1) * 32 + kloc];
    }
    const int gate = gunit >> 6;
    const float s = (gate == 2) ? K2E : -KE;
    wfrag[((ch * 16 + gt) * 64 + lane) * 8 + j] = f2bf(s * v);
}

#define CVTPK(D, A, B_)                                                      \
    asm("v_cvt_pk_bf16_f32 %0, %1, %2" : "=v"(D) : "v"(A), "v"(B_));

#define LOADMSG(DST, SS)                                                     \
    {                                                                        \
        const float* p_ = mrow + (SS) * 25 + kq;                             \
        if (kq < 24) {                                                       \
            float t0_ = p_[0], t1_ = p_[1], t2_ = p_[2], t3_ = p_[3];        \
            float t4_ = p_[4], t5_ = p_[5], t6_ = p_[6], t7_ = p_[7];        \
            CVTPK(DST.u.x, t0_, t1_) CVTPK(DST.u.y, t2_, t3_)                \
            CVTPK(DST.u.z, t4_, t5_) CVTPK(DST.u.w, t6_, t7_)                \
        } else {                                                             \
            float t0_ = p_[0], one_ = 1.0f;                                  \
            CVTPK(DST.u.x, t0_, one_)                                        \
            DST.u.y = 0u; DST.u.z = 0u; DST.u.w = 0u;                        \
        }                                                                    \
    }

#define STEP(S, CURB, NXTB, MC, MN)                                          \
    {                                                                        \
        if ((S) < 63) LOADMSG(MN, (S) + 1)                                   \
        bf16x8 bh[2];                                                        \
        _Pragma("unroll") for (int ch = 0; ch < 2; ++ch) {                   \
            int off_ = (l16 * 128 + ch * 64 + lq * 16) ^ swz;                \
            bh[ch] = *(const bf16x8*)((CURB) + off_);                        \
        }                                                                    \
        f32x4 acc[4];                                                        \
        _Pragma("unroll") for (int i = 0; i < 4; ++i)                        \
            acc[i] = (f32x4){0.f, 0.f, 0.f, 0.f};                           \
        _Pragma("unroll") for (int i = 0; i < 4; ++i)                        \
            acc[i] = __builtin_amdgcn_mfma_f32_16x16x32_bf16(                \
                w[0][i], MC.v, acc[i], 0, 0, 0);                             \
        _Pragma("unroll") for (int ch = 0; ch < 2; ++ch)                     \
            _Pragma("unroll") for (int i = 0; i < 4; ++i)                    \
                acc[i] = __builtin_amdgcn_mfma_f32_16x16x32_bf16(            \
                    w[1 + ch][i], bh[ch], acc[i], 0, 0, 0);                  \
        float hn[4];                                                         \
        _Pragma("unroll") for (int q = 0; q < 4; ++q) {                      \
            float ai = acc[0][q], af = acc[1][q];                            \
            float ag = acc[2][q], ao = acc[3][q];                            \
            float ti = __builtin_amdgcn_exp2f(ai);                           \
            float tf = __builtin_amdgcn_exp2f(af);                           \
            float to = __builtin_amdgcn_exp2f(ao);                           \
            float tg = __builtin_amdgcn_exp2f(-fabsf(ag));                   \
            float ig = (1.f - tg) *                                          \
                __builtin_amdgcn_rcpf((1.f + ti) * (1.f + tg));              \
            ig = copysignf(ig, ag);                                          \
            float fg = __builtin_amdgcn_rcpf(1.f + tf);                      \
            float cn = fmaf(fg, c[q], ig);                                   \
            c[q] = cn;                                                       \
            float tc = __builtin_amdgcn_exp2f(-fabsf(K2E * cn));             \
            float ot = (1.f - tc) *                                          \
                __builtin_amdgcn_rcpf((1.f + to) * (1.f + tc));              \
            hn[q] = copysignf(ot, cn);                                       \
        }                                                                    \
        unsigned r01_, r23_;                                                 \
        CVTPK(r01_, hn[0], hn[1]) CVTPK(r23_, hn[2], hn[3])                  \
        *(uint2*)((NXTB) + offw) = make_uint2(r01_, r23_);                   \
        __syncthreads();                                                     \
    }

__global__ __launch_bounds__(256, 4) void lstm_mfma(
    const float* __restrict__ msgs,
    const unsigned short* __restrict__ wfrag,
    const float* __restrict__ fcw,
    const float* __restrict__ fcb,
    float* __restrict__ out)
{
    // double-buffered h: buf = h[16 brows][64 units] bf16 = 2KB, x2
    __shared__ __align__(16) char lds[4096];

    const int tid  = threadIdx.x;
    const int lane = tid & 63;
    const int cg   = __builtin_amdgcn_readfirstlane(tid >> 6); // 0..3 (SGPR)
    const int l16  = lane & 15;                 // batch row within tile
    const int lq   = lane >> 4;                 // k-quad / unit-quad
    const int row0 = blockIdx.x * 16;
    const int kq   = lq * 8;                    // k base within chunk

    // weight A-fragments in VGPRs: gate i -> tile 4i+cg, 3 chunks
    bf16x8 w[3][4];
    #pragma unroll
    for (int ch = 0; ch < 3; ++ch)
        #pragma unroll
        for (int i = 0; i < 4; ++i)
            w[ch][i] = *(const bf16x8*)(wfrag + ((ch * 16 + 4 * i + cg) * 64 + lane) * 8);

    // zero h buffer 0 (2KB)
    for (int idx = tid; idx < 512; idx += 256) ((unsigned int*)lds)[idx] = 0u;

    float c[4] = {0.f, 0.f, 0.f, 0.f};

    const float* mrow = msgs + (long)(row0 + l16) * 1600;
    const int swz  = (l16 & 7) << 4;
    // this thread writes h[brow=l16][units 16cg+4lq .. +3] -> 8B
    const int offw = (l16 * 128 + cg * 32 + lq * 8) ^ swz;

    U16B m0, m1;
    LOADMSG(m0, 0)
    __syncthreads();

    char* b0 = (char*)lds;
    char* b1 = b0 + 2048;
    for (int s2 = 0; s2 < 64; s2 += 2) {
        STEP(s2,     b0, b1, m0, m1)
        STEP(s2 + 1, b1, b0, m1, m0)
    }

    // final h in b0 as h[brow][unit]. FC epilogue: thread -> (row, class)
    if (tid < 64) {
        const int r = tid >> 2, cls = tid & 3;
        if (cls < 3) {
            float a = fcb[cls];
            const int sw = (r & 7) << 4;
            #pragma unroll
            for (int u = 0; u < 64; ++u) {
                int off = (r * 128 + u * 2) ^ sw;
                float hv = bf2f(*(const unsigned short*)(b0 + off));
                a = fmaf(hv, fcw[cls * 64 + u], a);
            }
            out[(row0 + r) * 3 + cls] = a;
        }
    }
}

extern "C" void kernel_launch(void* const* d_in, const int* in_sizes, int n_in,
                              void* d_out, int out_size, void* d_ws, size_t ws_size,
                              hipStream_t stream) {
    const float* msgs = (const float*)d_in[0];
    const float* emb  = (const float*)d_in[1];
    const float* Wih  = (const float*)d_in[2];
    const float* Whh  = (const float*)d_in[3];
    const float* bih  = (const float*)d_in[4];
    const float* bhh  = (const float*)d_in[5];
    const float* fcw  = (const float*)d_in[6];
    const float* fcb  = (const float*)d_in[7];
    float* out = (float*)d_out;

    // ws: wfrag bf16[3*16*64*8] = 49152 B
    unsigned short* wfrag = (unsigned short*)d_ws;

    prep_kernel<<<48, 512, 0, stream>>>(emb, Wih, Whh, bih, bhh, wfrag);
    lstm_mfma<<<16384 / 16, 256, 0, stream>>>(msgs, wfrag, fcw, fcb, out);
}